// Round 7
// baseline (256.488 us; speedup 1.0000x reference)
//
#include <hip/hip_runtime.h>
#include <math.h>

#define BB 256
#define LL 500
#define EE 300
#define NROWS (BB * LL)      // 128000
#define ND 18                // dot vectors: aw3 r0-2, cw3, aw5 r0-4, cw5, aw7 r0-6, cw7
#define KSTEPS 19            // ceil(300/16), k 300..303 zero-padded in W
#define OPJ 26               // outputs per wave-job (32 rows - 6 halo)
#define JPB 20               // jobs per batch: 20*26 = 520 >= 500
#define DSTR 19              // dlds row stride (floats)

// ---------------------------------------------------------------------------
// R13: MFMA. Three structurally different scalar schedules (R8/R9/R12) all
// landed at ~77us: the invariant is the hand-rolled K-reduction itself --
// per 16 rows the scalar path pays 90 ds_read_b128 (weights), 288 DPP + 288
// dependent adds (reduction, ~half the VALU time with DPP wait-states), and
// 130+ live VGPRs (occupancy cap). v_mfma_f32_32x32x16_bf16 does the K-dot,
// weight broadcast, and accumulation in hardware. fp32 via 2-term bf16 split
// (3 MFMA: hi*hi + hi*lo + lo*hi; error ~1e-4 << 4e-3 tol). Wave = 32 rows
// = one job (26 outputs + halo): NO reduction, NO barriers, NO x/w LDS
// staging. W pre-split into per-lane fragments by a prepass (38.9 KB in
// d_ws, L2-hot for all 5120 waves). C/D layout is the m74/m101-verified
// col=lane&31, row=(reg&3)+8*(reg>>2)+4*(lane>>5). A/B k-ordering is safe
// by construction: A and B use the SAME (half,reg)->k map, and any
// consistent bijection gives the same dot product.
// ---------------------------------------------------------------------------

typedef short bf16x8 __attribute__((ext_vector_type(8)));   // 8 bf16 = 4 VGPR
typedef float f32x16 __attribute__((ext_vector_type(16)));  // 16 f32 acc

// prepass: per-lane B fragments, hi/lo bf16 split, all 19 k-steps.
// dword layout: wf[((s*64 + lane)*8) + q], q 0..3 = hi dwords, 4..7 = lo.
// fragment element r (k = 8*(lane>>5) + r) lives in dword q=r/2, half r&1.
__global__ void wfrag_build(
    const float* __restrict__ aw3, const float* __restrict__ aw5,
    const float* __restrict__ aw7, const float* __restrict__ cw3,
    const float* __restrict__ cw5, const float* __restrict__ cw7,
    unsigned int* __restrict__ wf)
{
    const int idx = blockIdx.x * 256 + threadIdx.x;   // 0 .. 9727
    const int s    = idx >> 9;                        // k-step
    const int r9   = idx & 511;
    const int lane = r9 >> 3;
    const int q    = r9 & 7;
    const int half = lane >> 5;
    const int d    = lane & 31;                       // output column
    const bool hiPart = (q < 4);
    const int qq   = q & 3;

    unsigned int outw = 0;
#pragma unroll
    for (int e = 0; e < 2; ++e) {
        const int k = s * 16 + half * 8 + qq * 2 + e;
        float w = 0.0f;
        if (d < ND && k < EE) {
            if      (d < 3)  w = aw3[d * EE + k];
            else if (d == 3) w = cw3[k];
            else if (d < 9)  w = aw5[(d - 4) * EE + k];
            else if (d == 9) w = cw5[k];
            else if (d < 17) w = aw7[(d - 10) * EE + k];
            else             w = cw7[k];
        }
        const unsigned int u = __float_as_uint(w);
        unsigned short h;
        if (hiPart) {
            h = (unsigned short)(u >> 16);            // truncated bf16 hi
        } else {
            const float whi = __uint_as_float(u & 0xFFFF0000u);
            const float lo  = w - whi;                // exact residual
            h = (unsigned short)(__float_as_uint(lo) >> 16);
        }
        outw |= ((unsigned int)h) << (16 * e);
    }
    wf[idx] = outw;
}

__global__ __launch_bounds__(256) void fused_kernel(
    const float* __restrict__ x, const unsigned int* __restrict__ wf,
    const float* __restrict__ ab3, const float* __restrict__ cb3,
    const float* __restrict__ ab5, const float* __restrict__ cb5,
    const float* __restrict__ ab7, const float* __restrict__ cb7,
    float* __restrict__ out)
{
    __shared__ float dlds[4][32 * DSTR];   // per-wave private patch, 9.7 KB

    const int tid   = threadIdx.x;
    const int wave  = tid >> 6;
    const int lane  = tid & 63;
    const int job   = blockIdx.x * 4 + wave;       // 0..5119, independent waves
    const int batch = job / JPB;
    const int t     = job - batch * JPB;           // 0..19
    const int l0    = t * OPJ - 3;                 // global l of local row 0

    // A-side: lane owns row (lane&31), k-half (lane>>5)*8 within each k-step
    const int row  = lane & 31;
    const int half = lane >> 5;
    int gr = l0 + row;
    gr = gr < 0 ? 0 : (gr >= LL ? LL - 1 : gr);
    const float* xr = x + ((size_t)batch * LL + gr) * EE + half * 8;

    const uint4* wfv = (const uint4*)wf;           // 2 uint4 per (s,lane)

    // ---- prologue: k-step 0 loads ----
    float4 xa = *(const float4*)(xr + 0);
    float4 xb = *(const float4*)(xr + 4);
    uint4  bh = wfv[(0 * 64 + lane) * 2 + 0];
    uint4  bl = wfv[(0 * 64 + lane) * 2 + 1];

    f32x16 acc;
#pragma unroll
    for (int i = 0; i < 16; ++i) acc[i] = 0.0f;

#pragma unroll 1
    for (int s = 0; s < KSTEPS; ++s) {
        // issue next k-step's loads (fly under this step's cvt + MFMA)
        float4 xa_n, xb_n; uint4 bh_n, bl_n;
        if (s + 1 < KSTEPS) {
            const int ko = (s + 1) * 16;
            xa_n = *(const float4*)(xr + ko);
            // tail guard: k 300..303 would read past row end for half==1;
            // W is zero there, so any in-bounds value works -> reload ko.
            const int off2 = ((s + 1 == KSTEPS - 1) && half) ? 0 : 4;
            xb_n = *(const float4*)(xr + ko + off2);
            bh_n = wfv[((s + 1) * 64 + lane) * 2 + 0];
            bl_n = wfv[((s + 1) * 64 + lane) * 2 + 1];
        }

        // fp32 -> bf16 hi/lo fragments (truncation split; residual exact)
        bf16x8 ahi, alo;
        const float xf[8] = {xa.x, xa.y, xa.z, xa.w, xb.x, xb.y, xb.z, xb.w};
#pragma unroll
        for (int e = 0; e < 8; ++e) {
            const unsigned int u = __float_as_uint(xf[e]);
            ahi[e] = (short)(u >> 16);
            const float hif = __uint_as_float(u & 0xFFFF0000u);
            const float lo  = xf[e] - hif;
            alo[e] = (short)(__float_as_uint(lo) >> 16);
        }
        const bf16x8 bhi = __builtin_bit_cast(bf16x8, bh);
        const bf16x8 blo = __builtin_bit_cast(bf16x8, bl);

        // D = Xhi*Whi + Xhi*Wlo + Xlo*Whi (lo*lo dropped, ~2^-16)
        acc = __builtin_amdgcn_mfma_f32_32x32x16_bf16(ahi, bhi, acc, 0, 0, 0);
        acc = __builtin_amdgcn_mfma_f32_32x32x16_bf16(ahi, blo, acc, 0, 0, 0);
        acc = __builtin_amdgcn_mfma_f32_32x32x16_bf16(alo, bhi, acc, 0, 0, 0);

        if (s + 1 < KSTEPS) { xa = xa_n; xb = xb_n; bh = bh_n; bl = bl_n; }
    }

    // ---- acc -> dlds: (reg,lane) -> row=(reg&3)+8*(reg>>2)+4*half, col=d ----
    float* dl = dlds[wave];
    const int d = lane & 31;
    if (d < ND) {
#pragma unroll
        for (int i = 0; i < 16; ++i) {
            const int rw = (i & 3) + 8 * (i >> 2) + 4 * half;
            const int g  = l0 + rw;
            const float vf = (g >= 0 && g < LL) ? 1.0f : 0.0f;
            dl[rw * DSTR + d] = acc[i] * vf;
        }
    }
    // same-wave LDS visibility only (R9/R10-proven): no barrier anywhere
    asm volatile("s_waitcnt lgkmcnt(0)" ::: "memory");

    // ---- epilogue: lane = center local row, all 3 branches ----
    if (lane >= 3 && lane < 3 + OPJ) {
        const int lo_ = l0 + lane;
        if (lo_ < LL) {
            const int r = batch * LL + lo_;
            const float cen3 = dl[lane * DSTR + 3];
            const float cen5 = dl[lane * DSTR + 9];
            const float cen7 = dl[lane * DSTR + 17];
            {
                float pre = 0.0f;
#pragma unroll
                for (int tp = 0; tp < 3; ++tp) pre += dl[(lane + tp - 1) * DSTR + tp];
                const float sg = 1.0f / (1.0f + expf(-(pre + ab3[0])));
                out[r] = tanhf(sg * cen3 + cb3[0]);
            }
            {
                float pre = 0.0f;
#pragma unroll
                for (int tp = 0; tp < 5; ++tp) pre += dl[(lane + tp - 2) * DSTR + 4 + tp];
                const float sg = 1.0f / (1.0f + expf(-(pre + ab5[0])));
                out[NROWS + r] = tanhf(sg * cen5 + cb5[0]);
            }
            {
                float pre = 0.0f;
#pragma unroll
                for (int tp = 0; tp < 7; ++tp) pre += dl[(lane + tp - 3) * DSTR + 10 + tp];
                const float sg = 1.0f / (1.0f + expf(-(pre + ab7[0])));
                out[2 * NROWS + r] = tanhf(sg * cen7 + cb7[0]);
            }
        }
    }
}

extern "C" void kernel_launch(void* const* d_in, const int* in_sizes, int n_in,
                              void* d_out, int out_size, void* d_ws, size_t ws_size,
                              hipStream_t stream) {
    const float* x   = (const float*)d_in[0];
    const float* aw3 = (const float*)d_in[1];
    const float* ab3 = (const float*)d_in[2];
    const float* cw3 = (const float*)d_in[3];
    const float* cb3 = (const float*)d_in[4];
    const float* aw5 = (const float*)d_in[5];
    const float* ab5 = (const float*)d_in[6];
    const float* cw5 = (const float*)d_in[7];
    const float* cb5 = (const float*)d_in[8];
    const float* aw7 = (const float*)d_in[9];
    const float* ab7 = (const float*)d_in[10];
    const float* cw7 = (const float*)d_in[11];
    const float* cb7 = (const float*)d_in[12];

    unsigned int* wf = (unsigned int*)d_ws;   // 19*64*8 dwords = 38.9 KB
    float* out = (float*)d_out;               // [out3 | out5 | out7]

    // prepass: per-lane hi/lo bf16 W fragments (9728 dwords = 38 blocks)
    wfrag_build<<<38, 256, 0, stream>>>(aw3, aw5, aw7, cw3, cw5, cw7, wf);

    // 5120 wave-jobs (256 batches x 20), 4 independent waves per block
    fused_kernel<<<(BB * JPB) / 4, 256, 0, stream>>>(
        x, wf, ab3, cb3, ab5, cb5, ab7, cb7, out);
}